// Round 4
// baseline (129.362 us; speedup 1.0000x reference)
//
#include <hip/hip_runtime.h>
#include <hip/hip_bf16.h>

#define BB 8
#define NN 512
#define DINC 128
#define DOUTC 128
#define HHC 8
#define EEC 16
#define DHC 16

typedef _Float16 h4 __attribute__((ext_vector_type(4)));
typedef float f32x4 __attribute__((ext_vector_type(4)));

__device__ __forceinline__ float wsum(float v){
#pragma unroll
  for (int o=1;o<64;o<<=1) v += __shfl_xor(v,o);
  return v;
}

// ---------- LN1 + Wp + Q/K/V projections: 8 rows per 128-thread block ----------
__global__ __launch_bounds__(128) void k_proj(
    const float* __restrict__ x,
    const float* __restrict__ g1, const float* __restrict__ b1,
    const float* __restrict__ Wp, const float* __restrict__ bp,
    const float* __restrict__ Wq, const float* __restrict__ Wk, const float* __restrict__ Wv,
    float* __restrict__ xp, _Float16* __restrict__ Qh, _Float16* __restrict__ Kh, _Float16* __restrict__ Vh)
{
  const int R = 8, P = 12;
  __shared__ float xln[DINC*P];
  __shared__ float xps[DINC*P];
  __shared__ float part[2][R][2];
  int tid = threadIdx.x, w = tid>>6, lane = tid&63;
  int row0 = blockIdx.x * R;
  float v[R];
#pragma unroll
  for (int r=0;r<R;++r) v[r] = x[(size_t)(row0+r)*DINC + tid];
  float gg = g1[tid], bbv = b1[tid];
#pragma unroll
  for (int r=0;r<R;++r){
    float s = wsum(v[r]);
    float q = wsum(v[r]*v[r]);
    if (lane==0){ part[w][r][0]=s; part[w][r][1]=q; }
  }
  __syncthreads();
#pragma unroll
  for (int r=0;r<R;++r){
    float s = part[0][r][0]+part[1][r][0];
    float q = part[0][r][1]+part[1][r][1];
    float mean = s*(1.f/DINC);
    float var  = q*(1.f/DINC) - mean*mean;
    float rstd = rsqrtf(var + 1e-5f);
    xln[tid*P + r] = (v[r]-mean)*rstd*gg + bbv;
  }
  __syncthreads();
  int j = tid;
  float acc[R];
  {
    float bj = bp[j];
#pragma unroll
    for (int r=0;r<R;++r) acc[r]=bj;
    for (int i=0;i<DINC;++i){
      float wv = Wp[i*DOUTC + j];
      const float4* xa = (const float4*)&xln[i*P];
      float4 a = xa[0], b = xa[1];
      acc[0]+=a.x*wv; acc[1]+=a.y*wv; acc[2]+=a.z*wv; acc[3]+=a.w*wv;
      acc[4]+=b.x*wv; acc[5]+=b.y*wv; acc[6]+=b.z*wv; acc[7]+=b.w*wv;
    }
#pragma unroll
    for (int r=0;r<R;++r){
      xps[j*P + r] = acc[r];
      xp[(size_t)(row0+r)*DOUTC + j] = acc[r];
    }
  }
  __syncthreads();
  const float* Ws[3] = {Wq, Wk, Wv};
  _Float16* Os[3] = {Qh, Kh, Vh};
#pragma unroll
  for (int mmat=0;mmat<3;++mmat){
    const float* W = Ws[mmat];
#pragma unroll
    for (int r=0;r<R;++r) acc[r]=0.f;
    for (int i=0;i<DINC;++i){
      float wv = W[i*DOUTC + j];
      const float4* xa = (const float4*)&xps[i*P];
      float4 a = xa[0], b = xa[1];
      acc[0]+=a.x*wv; acc[1]+=a.y*wv; acc[2]+=a.z*wv; acc[3]+=a.w*wv;
      acc[4]+=b.x*wv; acc[5]+=b.y*wv; acc[6]+=b.z*wv; acc[7]+=b.w*wv;
    }
    int h = j>>4, d = j&15;
    _Float16* O = Os[mmat];
#pragma unroll
    for (int r=0;r<R;++r){
      int row = row0+r; int bidx = row>>9, n = row&(NN-1);
      O[(((size_t)bidx*HHC + h)*NN + n)*DHC + d] = (_Float16)acc[r];
    }
  }
}

// ---------- FUSED edge-MLP + attention: block=(b, 8-row tile), 8 waves ----------
// Per 64-m chunk: wave w computes edge MLP (transposed MFMA trick, mask baked as
// -30000) for row n=w into biasL[h][n][m]; K/V staged to LDS; then wave w = head w
// runs swapped QK^T + exp(s-6) (no max-sub, scores bounded) + PV accumulate.
__global__ __launch_bounds__(512,2) void k_fused(
  const float* __restrict__ ea, const int* __restrict__ adj,
  const float* __restrict__ eg, const float* __restrict__ ebi,
  const float* __restrict__ We1, const float* __restrict__ be1,
  const float* __restrict__ We2, const float* __restrict__ be2,
  const _Float16* __restrict__ Qh, const _Float16* __restrict__ Kh,
  const _Float16* __restrict__ Vh, float* __restrict__ ctxb)
{
  __shared__ _Float16 biasL[8*8*68];        // [h][n][m pad68] 8.5KB
  __shared__ _Float16 Kl[8*64*24];          // [h][m][d pad24] 24KB (16B-aligned stores)
  __shared__ _Float16 Vt[8*16*68];          // [h][d][m pad68] 17KB
  __shared__ unsigned long long mrow[8][8];

  int tid = threadIdx.x, w = tid>>6, lane = tid&63;
  int c = lane&15, g = lane>>4;
  int blk = blockIdx.x;
  int b = blk>>6, tile = blk&63;
  int n0 = tile*8;

  // adjacency bitmask (+self loop) for the 8 rows of this tile
#pragma unroll
  for (int k=0;k<8;++k){
    int row = n0+k;
    int val = (adj[((size_t)b*NN + row)*NN + tid] != 0) || (row == tid);
    unsigned long long bal = __ballot(val);
    if (lane==0) mrow[k][w] = bal;
  }

  // MLP weight A-fragments (transposed layers; identical math to verified k_edge)
  h4 w1a,w1b,w2a,w2b;
#pragma unroll
  for (int j=0;j<4;++j){
    w1a[j] = (_Float16)We1[(4*g+j)*32 + c];
    w1b[j] = (_Float16)We1[(4*g+j)*32 + 16 + c];
    w2a[j] = (_Float16)((c<8)? We2[(4*g+j)*HHC + c] : 0.f);
    w2b[j] = (_Float16)((c<8)? We2[(16+4*g+j)*HHC + c] : 0.f);
  }
  float4 b1a = *(const float4*)(be1 + 4*g);
  float4 b1b = *(const float4*)(be1 + 16 + 4*g);
  float4 b2r = *(const float4*)(be2 + (g&1)*4);
  float4 G4  = *(const float4*)(eg  + 4*g);
  float4 Bv4 = *(const float4*)(ebi + 4*g);

  // Q B-fragment for head w (c&7: tile has 8 valid rows; cols 8-15 are discarded dups)
  h4 qf = *(const h4*)(Qh + (((size_t)b*HHC + w)*NN + n0 + (c&7))*DHC + 4*g);

  const float* eaRow = ea + (((size_t)b*NN + n0 + w)*NN)*EEC;   // this wave's MLP row

  f32x4 acc = {0.f,0.f,0.f,0.f};
  float rowsum = 0.f;

  float4 erA[4], erB[4];
#pragma unroll
  for (int mg=0;mg<4;++mg)
    erA[mg] = *(const float4*)(eaRow + (size_t)(mg*16 + c)*EEC + 4*g);

  __syncthreads();   // mrow visible to all waves

  auto CHUNK = [&](int ch, float4 (&ecur)[4], float4 (&enxt)[4], bool pref){
    // ---- edge MLP for row n=w, 4 groups of 16 m
#pragma unroll
    for (int mg=0;mg<4;++mg){
      float4 v = ecur[mg];
      float s = v.x+v.y+v.z+v.w;
      float q = v.x*v.x+v.y*v.y+v.z*v.z+v.w*v.w;
      s += __shfl_xor(s,16); s += __shfl_xor(s,32);
      q += __shfl_xor(q,16); q += __shfl_xor(q,32);
      float mean = s*(1.f/EEC);
      float var  = q*(1.f/EEC) - mean*mean;
      float rstd = rsqrtf(var + 1e-5f);
      h4 ef;
      ef[0]=(_Float16)((v.x-mean)*rstd*G4.x + Bv4.x);
      ef[1]=(_Float16)((v.y-mean)*rstd*G4.y + Bv4.y);
      ef[2]=(_Float16)((v.z-mean)*rstd*G4.z + Bv4.z);
      ef[3]=(_Float16)((v.w-mean)*rstd*G4.w + Bv4.w);
      f32x4 d1a = {b1a.x,b1a.y,b1a.z,b1a.w};
      f32x4 d1b = {b1b.x,b1b.y,b1b.z,b1b.w};
      d1a = __builtin_amdgcn_mfma_f32_16x16x16f16(w1a, ef, d1a, 0,0,0);
      d1b = __builtin_amdgcn_mfma_f32_16x16x16f16(w1b, ef, d1b, 0,0,0);
      h4 hfa,hfb;
#pragma unroll
      for (int r=0;r<4;++r){
        hfa[r]=(_Float16)fmaxf(d1a[r],0.f);
        hfb[r]=(_Float16)fmaxf(d1b[r],0.f);
      }
      f32x4 d2 = {0.f,0.f,0.f,0.f};
      d2 = __builtin_amdgcn_mfma_f32_16x16x16f16(w2a, hfa, d2, 0,0,0);
      d2 = __builtin_amdgcn_mfma_f32_16x16x16f16(w2b, hfb, d2, 0,0,0);
      if (g<2){
        unsigned long long wm = mrow[w][ch];
#pragma unroll
        for (int r=0;r<4;++r){
          float y = d2[r] + ((const float*)&b2r)[r];
          y = fminf(fmaxf(2.f*y,-30.f),30.f);
          float ex = __expf(y);
          float t = (ex-1.f)/(ex+1.f);                 // tanh
          bool ok = (wm >> (mg*16+c)) & 1ull;
          biasL[((4*g+r)*8 + w)*68 + mg*16 + c] = ok ? (_Float16)(5.f*t) : (_Float16)(-30000.f);
        }
      }
    }
    // ---- stage K (row-major, pad24) and V (transposed, pad68) for this chunk
#pragma unroll
    for (int s2=0;s2<2;++s2){
      int i = tid + 512*s2;
      int hh = i>>7, rem = i&127, m = rem>>1, hf = rem&1;
      size_t off = (((size_t)b*HHC + hh)*NN + ch*64 + m)*DHC + hf*8;
      float4 kv = *(const float4*)(Kh + off);
      float4 vv = *(const float4*)(Vh + off);
      *(float4*)(Kl + (hh*64 + m)*24 + hf*8) = kv;
      const _Float16* vp = (const _Float16*)&vv;
#pragma unroll
      for (int jj=0;jj<8;++jj) Vt[(hh*16 + hf*8 + jj)*68 + m] = vp[jj];
    }
    __syncthreads();
    // ---- prefetch next ea chunk (in flight during attention phase)
    if (pref){
#pragma unroll
      for (int mg=0;mg<4;++mg)
        enxt[mg] = *(const float4*)(eaRow + (size_t)((ch+1)*64 + mg*16 + c)*EEC + 4*g);
    }
    // ---- attention on this chunk, head h = w
#pragma unroll
    for (int t=0;t<4;++t){
      h4 kf = *(const h4*)(Kl + (w*64 + 16*t + c)*24 + 4*g);
      f32x4 zero = {0.f,0.f,0.f,0.f};
      f32x4 d = __builtin_amdgcn_mfma_f32_16x16x16f16(kf, qf, zero, 0,0,0);
      h4 e4 = *(const h4*)(biasL + ((size_t)(w*8 + (c&7)))*68 + 16*t + 4*g);
      h4 pa;
#pragma unroll
      for (int r=0;r<4;++r){
        float sv = d[r]*0.25f + (float)e4[r];
        sv = fmaxf(sv,0.f) + 0.2f*fminf(sv,0.f);       // LeakyReLU(0.2)
        float p = __expf(sv - 6.f);                    // constant shift, no max-sub
        rowsum += p;
        pa[r] = (_Float16)p;
      }
      h4 vf = *(const h4*)(Vt + (w*16 + c)*68 + 16*t + 4*g);
      acc = __builtin_amdgcn_mfma_f32_16x16x16f16(pa, vf, acc, 0,0,0);
    }
    __syncthreads();
  };

#pragma unroll
  for (int cc=0; cc<4; ++cc){
    CHUNK(2*cc,   erA, erB, true);
    CHUNK(2*cc+1, erB, erA, (2*cc+1)<7);
  }

  rowsum += __shfl_xor(rowsum,16);
  rowsum += __shfl_xor(rowsum,32);
  float sr[4];
#pragma unroll
  for (int r=0;r<4;++r) sr[r] = __shfl(rowsum, 4*g + r);
  if (g<2){
#pragma unroll
    for (int r=0;r<4;++r)
      ctxb[((size_t)b*NN + n0 + 4*g + r)*DOUTC + w*DHC + c] = acc[r]/sr[r];
  }
}

// ---------- h = xp+ctx; LN2; FFN; out = h + ffn : 16 rows per block ----------
__global__ __launch_bounds__(256) void k_ffn(
  const float* __restrict__ xp, const float* __restrict__ ctxb,
  const float* __restrict__ g2, const float* __restrict__ b2v,
  const float* __restrict__ W1, const float* __restrict__ bb1,
  const float* __restrict__ W2, const float* __restrict__ bb2,
  float* __restrict__ out)
{
  const int R = 16, P = 20;
  __shared__ float hrow[R][DOUTC];
  __shared__ float hn[DOUTC*P];
  __shared__ float hid[256*P];
  int tid=threadIdx.x, w=tid>>6, lane=tid&63;
  int row0 = blockIdx.x*R;
  for (int i=tid;i<R*DOUTC;i+=256){
    int r=i>>7, c=i&127;
    size_t gi = (size_t)(row0+r)*DOUTC + c;
    hrow[r][c] = xp[gi] + ctxb[gi];
  }
  __syncthreads();
  float ga=g2[lane], gb=g2[lane+64], ba=b2v[lane], bbx=b2v[lane+64];
  for (int r=w; r<R; r+=4){
    float a = hrow[r][lane], c = hrow[r][lane+64];
    float s = wsum(a+c);
    float q = wsum(a*a+c*c);
    float mean = s*(1.f/DOUTC);
    float var  = q*(1.f/DOUTC)-mean*mean;
    float rstd = rsqrtf(var+1e-5f);
    hn[lane*P + r]      = (a-mean)*rstd*ga + ba;
    hn[(lane+64)*P + r] = (c-mean)*rstd*gb + bbx;
  }
  __syncthreads();
  {
    int j=tid;
    float acc[R];
    float bj = bb1[j];
#pragma unroll
    for (int r=0;r<R;++r) acc[r]=bj;
    for (int i=0;i<DOUTC;++i){
      float wv = W1[i*256 + j];
      const float4* xa = (const float4*)&hn[i*P];
      float4 a=xa[0], b=xa[1], c=xa[2], d=xa[3];
      acc[0]+=a.x*wv;  acc[1]+=a.y*wv;  acc[2]+=a.z*wv;  acc[3]+=a.w*wv;
      acc[4]+=b.x*wv;  acc[5]+=b.y*wv;  acc[6]+=b.z*wv;  acc[7]+=b.w*wv;
      acc[8]+=c.x*wv;  acc[9]+=c.y*wv;  acc[10]+=c.z*wv; acc[11]+=c.w*wv;
      acc[12]+=d.x*wv; acc[13]+=d.y*wv; acc[14]+=d.z*wv; acc[15]+=d.w*wv;
    }
#pragma unroll
    for (int r=0;r<R;++r) hid[j*P+r] = fmaxf(acc[r],0.f);
  }
  __syncthreads();
  {
    int j2 = tid&127, r0 = (tid>>7)*8;
    float acc[8];
#pragma unroll
    for (int r=0;r<8;++r) acc[r]=0.f;
    for (int i=0;i<256;++i){
      float wv = W2[i*DOUTC + j2];
      const float4* xa = (const float4*)&hid[i*P + r0];
      float4 a=xa[0], b=xa[1];
      acc[0]+=a.x*wv; acc[1]+=a.y*wv; acc[2]+=a.z*wv; acc[3]+=a.w*wv;
      acc[4]+=b.x*wv; acc[5]+=b.y*wv; acc[6]+=b.z*wv; acc[7]+=b.w*wv;
    }
    float bj = bb2[j2];
#pragma unroll
    for (int r=0;r<8;++r)
      out[(size_t)(row0+r0+r)*DOUTC + j2] = hrow[r0+r][j2] + acc[r] + bj;
  }
}

extern "C" void kernel_launch(void* const* d_in, const int* in_sizes, int n_in,
                              void* d_out, int out_size, void* d_ws, size_t ws_size,
                              hipStream_t stream)
{
  const float* x     = (const float*)d_in[0];
  const int*   adj   = (const int*)  d_in[1];
  const float* ea    = (const float*)d_in[2];
  const float* ln1_g = (const float*)d_in[3];
  const float* ln1_b = (const float*)d_in[4];
  const float* Wp    = (const float*)d_in[5];
  const float* bp    = (const float*)d_in[6];
  const float* eln_g = (const float*)d_in[7];
  const float* eln_b = (const float*)d_in[8];
  const float* We1   = (const float*)d_in[9];
  const float* be1   = (const float*)d_in[10];
  const float* We2   = (const float*)d_in[11];
  const float* be2   = (const float*)d_in[12];
  const float* Wq    = (const float*)d_in[13];
  const float* Wk    = (const float*)d_in[14];
  const float* Wv    = (const float*)d_in[15];
  const float* ffW1  = (const float*)d_in[16];
  const float* ffb1  = (const float*)d_in[17];
  const float* ffW2  = (const float*)d_in[18];
  const float* ffb2  = (const float*)d_in[19];
  const float* ln2_g = (const float*)d_in[20];
  const float* ln2_b = (const float*)d_in[21];
  float* out = (float*)d_out;

  char* ws = (char*)d_ws;
  float*    xp  = (float*)(ws);                       // 2MB
  float*    ctx = (float*)(ws + ((size_t)2<<20));     // 2MB
  _Float16* Qh  = (_Float16*)(ws + ((size_t)4<<20));  // 1MB
  _Float16* Kh  = (_Float16*)(ws + ((size_t)5<<20));  // 1MB
  _Float16* Vh  = (_Float16*)(ws + ((size_t)6<<20));  // 1MB

  k_proj<<<(BB*NN)/8, 128, 0, stream>>>(x, ln1_g, ln1_b, Wp, bp, Wq, Wk, Wv, xp, Qh, Kh, Vh);
  k_fused<<<BB*(NN/8), 512, 0, stream>>>(ea, adj, eln_g, eln_b, We1, be1, We2, be2,
                                         Qh, Kh, Vh, ctx);
  k_ffn<<<(BB*NN)/16, 256, 0, stream>>>(xp, ctx, ln2_g, ln2_b, ffW1, ffb1, ffW2, ffb2, out);
}